// Round 9
// baseline (104.923 us; speedup 1.0000x reference)
//
#include <hip/hip_runtime.h>
#include <math.h>

#define NTOT 6148
#define NB 64
#define DM 512
#define SCALE_F 0.17677669529663687f

typedef __attribute__((ext_vector_type(8))) short bf16x8;
typedef __attribute__((ext_vector_type(4))) float f32x4;

__device__ __forceinline__ short f2bf(float f) {
  union { float f; unsigned u; } v; v.f = f;
  unsigned r = (v.u + 0x7fffu + ((v.u >> 16) & 1u)) >> 16;
  return (short)r;
}

__device__ __forceinline__ void gl_lds16(const void* g, void* l) {
  auto gp = (const __attribute__((address_space(1))) unsigned*)(unsigned long long)(uintptr_t)g;
  auto lp = (__attribute__((address_space(3))) unsigned*)(unsigned long long)(uintptr_t)l;
  __builtin_amdgcn_global_load_lds(gp, lp, 16, 0, 0);
}

// ---------------- starts from batch array ----------------
__global__ __launch_bounds__(256) void k_starts(const int* __restrict__ batch,
                                                int* __restrict__ starts) {
  int i = blockIdx.x * 256 + threadIdx.x;
  if (i >= NTOT) return;
  int b = batch[i];
  if (i == 0) starts[b] = 0;
  else if (batch[i - 1] != b) starts[b] = i;
  if (i == NTOT - 1) starts[NB] = NTOT;
}

// ---------------- f32 -> bf16 conversion (x + 4 weight matrices) ----------------
__global__ __launch_bounds__(256) void k_cvt(const float* __restrict__ x,
                                             const float* __restrict__ wq,
                                             const float* __restrict__ wk,
                                             const float* __restrict__ wv,
                                             const float* __restrict__ wp,
                                             short* __restrict__ xb,
                                             short* __restrict__ wqb,
                                             short* __restrict__ wkb,
                                             short* __restrict__ wvb,
                                             short* __restrict__ wpb) {
  const int bid = blockIdx.x;
  const float* s; short* d; long off;
  if (bid < 1537) {  // 1537*2048 == NTOT*512 exactly
    s = x; d = xb;
    off = ((long)bid * 256 + threadIdx.x) * 8;
  } else {
    int wi = (bid - 1537) >> 7;  // 128 blocks per 512x512 matrix
    s = (wi == 0) ? wq : (wi == 1) ? wk : (wi == 2) ? wv : wp;
    d = (wi == 0) ? wqb : (wi == 1) ? wkb : (wi == 2) ? wvb : wpb;
    off = ((long)((bid - 1537) & 127) * 256 + threadIdx.x) * 8;
  }
  float4 v0 = *(const float4*)(s + off);
  float4 v1 = *(const float4*)(s + off + 4);
  bf16x8 o;
  o[0] = f2bf(v0.x); o[1] = f2bf(v0.y); o[2] = f2bf(v0.z); o[3] = f2bf(v0.w);
  o[4] = f2bf(v1.x); o[5] = f2bf(v1.y); o[6] = f2bf(v1.z); o[7] = f2bf(v1.w);
  *(bf16x8*)(d + off) = o;
}

// ---------------- bf16 MFMA GEMM, counted-vmcnt pipeline (T3+T4) ----------------
// C = A[M][512](bf16) @ W[N][512](bf16)^T + bias. 128x128 tile, BK=32, 4 waves.
// 4-deep LDS ring, prefetch depth 2, raw s_barrier + s_waitcnt vmcnt(8) — loads
// stay in flight across barriers (never drain to 0 in the main loop).
template <bool BF16OUT>
__global__ __launch_bounds__(256) void k_gemm_mfma(
    const short* __restrict__ Abf,
    const short* __restrict__ W0, const short* __restrict__ W1, const short* __restrict__ W2,
    const float* __restrict__ b0, const float* __restrict__ b1, const float* __restrict__ b2,
    const float* __restrict__ resid, void* __restrict__ Cv, int ldc, int M) {
  __shared__ __align__(16) short As[4][128][32];
  __shared__ __align__(16) short Bs[4][128][32];
  const int tid = threadIdx.x;
  const int w = tid >> 6, l = tid & 63;
  const int m0 = blockIdx.y * 128;
  const int n0 = blockIdx.x * 128;
  const int sel = n0 >> 9;
  const short* Wt = (sel == 0) ? W0 : (sel == 1) ? W1 : W2;
  const float* bt = (sel == 0) ? b0 : (sel == 1) ? b1 : b2;
  const int nl0 = n0 & 511;
  const int wr = w >> 1, wc = w & 1;
  const int lr = l >> 2;        // row within 16-row DMA group
  const int lc = (l & 3) * 8;   // short offset of this lane's 16B chunk
  const int r0 = w * 32 + lr, r1 = r0 + 16;
  const long ga0 = (long)min(m0 + r0, M - 1) * 512 + lc;
  const long ga1 = (long)min(m0 + r1, M - 1) * 512 + lc;
  const long gb0 = (long)(nl0 + r0) * 512 + lc;
  const long gb1 = (long)(nl0 + r1) * 512 + lc;
  const int fr = l & 15, fs = (l >> 4) * 8;

  f32x4 acc[4][4];
#pragma unroll
  for (int m = 0; m < 4; m++)
#pragma unroll
    for (int n = 0; n < 4; n++) acc[m][n] = (f32x4){0.f, 0.f, 0.f, 0.f};

  auto stage = [&](int kt, int rb) {
    const int k0 = kt * 32;
    gl_lds16(Abf + ga0 + k0, &As[rb][w * 32][0]);
    gl_lds16(Abf + ga1 + k0, &As[rb][w * 32 + 16][0]);
    gl_lds16(Wt + gb0 + k0, &Bs[rb][w * 32][0]);
    gl_lds16(Wt + gb1 + k0, &Bs[rb][w * 32 + 16][0]);
  };
  auto compute = [&](int rb) {
    bf16x8 af[4], bfr[4];
#pragma unroll
    for (int m = 0; m < 4; m++) af[m] = *(const bf16x8*)&As[rb][wr * 64 + m * 16 + fr][fs];
#pragma unroll
    for (int n = 0; n < 4; n++) bfr[n] = *(const bf16x8*)&Bs[rb][wc * 64 + n * 16 + fr][fs];
#pragma unroll
    for (int m = 0; m < 4; m++)
#pragma unroll
      for (int n = 0; n < 4; n++)
        acc[m][n] = __builtin_amdgcn_mfma_f32_16x16x32_bf16(af[m], bfr[n], acc[m][n], 0, 0, 0);
  };

  // prologue: tiles 0,1 in flight
  stage(0, 0);
  stage(1, 1);
  // main loop: stage t+2, keep <=2 tiles (8 loads/wave) in flight across barrier
  for (int t = 0; t < 14; t++) {
    stage(t + 2, (t + 2) & 3);
    asm volatile("s_waitcnt vmcnt(8)" ::: "memory");  // tile t's 4 loads retired
    __builtin_amdgcn_s_barrier();
    compute(t & 3);
  }
  asm volatile("s_waitcnt vmcnt(4)" ::: "memory");    // tile 14 retired
  __builtin_amdgcn_s_barrier();
  compute(14 & 3);
  asm volatile("s_waitcnt vmcnt(0)" ::: "memory");    // tile 15 retired
  __builtin_amdgcn_s_barrier();
  compute(15 & 3);

  // epilogue: C/D layout col=lane&15, row=(lane>>4)*4+j
  const int er = (l >> 4) * 4, ec = l & 15;
#pragma unroll
  for (int n = 0; n < 4; n++) {
    const int col = n0 + wc * 64 + n * 16 + ec;
    const float bv = bt[col & 511];
#pragma unroll
    for (int m = 0; m < 4; m++) {
      const int rowb = m0 + wr * 64 + m * 16 + er;
#pragma unroll
      for (int j = 0; j < 4; j++) {
        const int row = rowb + j;
        if (row < M) {
          float v = acc[m][n][j] + bv;
          if (resid) v += resid[(long)row * 512 + col];
          if (BF16OUT) ((short*)Cv)[(long)row * ldc + col] = f2bf(v);
          else ((float*)Cv)[(long)row * ldc + col] = v;
        }
      }
    }
  }
}

// ---------------- MFMA attention: one block per (h, b), 4 waves x 32 q-rows ----
// Bias panel DMA'd (global_load_lds, f32) into a per-wave LDS strip; softmax
// reads bias from LDS, then unnormalized bf16 P overwrites the same strip
// (reads of each m-half complete before its P writes; wave-local in-order LDS).
__global__ __launch_bounds__(256, 2) void k_attn(const short* __restrict__ QKVbf,
                                                 const float* __restrict__ bias,
                                                 const int* __restrict__ starts,
                                                 short* __restrict__ Obf) {
  __shared__ __align__(16) float BiasP[4][16][264];  // per-wave: 16 x (2 rows x 128 + 8 pad)
  __shared__ __align__(16) short Vtb[32][136];       // V transposed (rows = d)
  const int h = blockIdx.x, b = blockIdx.y;
  const int s0 = starts[b], cnt = starts[b + 1] - s0;
  const int tid = threadIdx.x, l = tid & 63, w = tid >> 6;
  const int wq0 = w * 32;
  const int lg = l >> 4, lk = l & 15, fs = lg * 8;
  const bool active = wq0 < cnt;
  short* Pw = (short*)&BiasP[w][0][0];  // P rows: 32 x 136 shorts, aliases bias strip

  // ---- issue V reg loads (own 32 k-rows, clamped => finite) ----
  const int u = l >> 2, c = (l & 3) * 8;
  const short* vbase = QKVbf + 1024 + h * 32 + c;
  const bf16x8 v0 = *(const bf16x8*)(vbase + (long)(s0 + min(wq0 + u, cnt - 1)) * 1536);
  const bf16x8 v1 = *(const bf16x8*)(vbase + (long)(s0 + min(wq0 + u + 16, cnt - 1)) * 1536);

  // ---- issue 16x 1KB bias DMA (fire-and-forget, no VGPRs) ----
  const float* bbase = bias + ((long)(b * 16 + h) << 14);
  if (active) {
    const float* bsrc = bbase + (long)wq0 * 128 + l * 4;  // lane's 16B within each 1KB chunk
#pragma unroll
    for (int t = 0; t < 16; t++)
      gl_lds16(bsrc + t * 256, &BiasP[w][t][0]);
  }

  // ---- issue Q/K fragment reg loads ----
  bf16x8 aq[2], bk[8];
  if (active) {
    const short* qbase = QKVbf + h * 32 + fs;
#pragma unroll
    for (int m = 0; m < 2; m++)
      aq[m] = *(const bf16x8*)(qbase + (long)(s0 + min(wq0 + m * 16 + lk, cnt - 1)) * 1536);
#pragma unroll
    for (int n = 0; n < 8; n++)
      bk[n] = *(const bf16x8*)(qbase + 512 + (long)(s0 + min(n * 16 + lk, cnt - 1)) * 1536);
  }

  // ---- V scatter-transpose into LDS (rows >= cnt finite, killed by P==0) ----
#pragma unroll
  for (int i = 0; i < 8; i++) Vtb[c + i][wq0 + u] = v0[i];
#pragma unroll
  for (int i = 0; i < 8; i++) Vtb[c + i][wq0 + u + 16] = v1[i];

  f32x4 S[2][8];
  float invs[2][4];
  if (active) {
    // ---- S = Q K^T (16 MFMA) ----
#pragma unroll
    for (int n = 0; n < 8; n++)
#pragma unroll
      for (int m = 0; m < 2; m++)
        S[m][n] = __builtin_amdgcn_mfma_f32_16x16x32_bf16(aq[m], bk[n],
                                                          (f32x4){0.f, 0.f, 0.f, 0.f}, 0, 0, 0);
    // DMA has no dest reg: explicitly drain before reading the bias strip
    asm volatile("s_waitcnt vmcnt(0)" ::: "memory");
    __builtin_amdgcn_sched_barrier(0);

    // ---- bias(LDS,f32) + scale + mask + softmax; unnormalized P -> strip ----
#pragma unroll
    for (int m = 0; m < 2; m++) {
      const int rb = m * 16 + lg * 4;  // local q row base
#pragma unroll
      for (int n = 0; n < 8; n++) {
        const int k = n * 16 + lk;
        const bool kok = k < cnt;
#pragma unroll
        for (int j = 0; j < 4; j++) {
          const int r = rb + j;
          const float sv = S[m][n][j] * SCALE_F + BiasP[w][r >> 1][(r & 1) * 128 + k];
          S[m][n][j] = kok ? sv : -1e30f;
        }
      }
#pragma unroll
      for (int j = 0; j < 4; j++) {
        float mx = S[m][0][j];
#pragma unroll
        for (int n = 1; n < 8; n++) mx = fmaxf(mx, S[m][n][j]);
        mx = fmaxf(mx, __shfl_xor(mx, 1));
        mx = fmaxf(mx, __shfl_xor(mx, 2));
        mx = fmaxf(mx, __shfl_xor(mx, 4));
        mx = fmaxf(mx, __shfl_xor(mx, 8));
        float sum = 0.f;
#pragma unroll
        for (int n = 0; n < 8; n++) {
          const float p = __expf(S[m][n][j] - mx);
          S[m][n][j] = p;
          sum += p;
        }
        sum += __shfl_xor(sum, 1);
        sum += __shfl_xor(sum, 2);
        sum += __shfl_xor(sum, 4);
        sum += __shfl_xor(sum, 8);
        invs[m][j] = 1.f / sum;
        const int r = rb + j;
#pragma unroll
        for (int n = 0; n < 8; n++) Pw[r * 136 + n * 16 + lk] = f2bf(S[m][n][j]);
      }
    }
  }

  __syncthreads();  // V (cross-wave) visibility; P/bias strips are wave-local
  if (!active) return;

  // ---- O = P V (16 MFMA), same-wave LDS RAW ----
  f32x4 O[2][2];
#pragma unroll
  for (int m = 0; m < 2; m++)
#pragma unroll
    for (int dt = 0; dt < 2; dt++) O[m][dt] = (f32x4){0.f, 0.f, 0.f, 0.f};
#pragma unroll
  for (int kc = 0; kc < 4; kc++) {
    bf16x8 pa[2], vb[2];
#pragma unroll
    for (int m = 0; m < 2; m++)
      pa[m] = *(const bf16x8*)&Pw[(m * 16 + lk) * 136 + kc * 32 + fs];
#pragma unroll
    for (int dt = 0; dt < 2; dt++) vb[dt] = *(const bf16x8*)&Vtb[dt * 16 + lk][kc * 32 + fs];
#pragma unroll
    for (int m = 0; m < 2; m++)
#pragma unroll
      for (int dt = 0; dt < 2; dt++)
        O[m][dt] = __builtin_amdgcn_mfma_f32_16x16x32_bf16(pa[m], vb[dt], O[m][dt], 0, 0, 0);
  }
  // ---- store O (bf16), fold in 1/sum ----
#pragma unroll
  for (int m = 0; m < 2; m++) {
    const int qb0 = wq0 + m * 16 + lg * 4;
#pragma unroll
    for (int j = 0; j < 4; j++) {
      if (qb0 + j < cnt) {
        short* orow = Obf + (long)(s0 + qb0 + j) * 512 + h * 32;
#pragma unroll
        for (int dt = 0; dt < 2; dt++)
          orow[dt * 16 + lk] = f2bf(O[m][dt][j] * invs[m][j]);
      }
    }
  }
}

// ---------------- LayerNorm (residual pre-added), one wave per row ----------------
__global__ __launch_bounds__(256) void k_lnp(const float* __restrict__ pre,
                                             const float* __restrict__ lw,
                                             const float* __restrict__ lb,
                                             float* __restrict__ out) {
  const int row = blockIdx.x * 4 + (threadIdx.x >> 6);
  if (row >= NTOT) return;
  const int lane = threadIdx.x & 63;
  const float* pr = pre + (long)row * 512 + lane * 8;
  float4 p0 = *(const float4*)pr;
  float4 p1 = *(const float4*)(pr + 4);
  float v[8] = {p0.x, p0.y, p0.z, p0.w, p1.x, p1.y, p1.z, p1.w};
  float s = 0.f, s2 = 0.f;
#pragma unroll
  for (int j = 0; j < 8; j++) { s += v[j]; s2 += v[j] * v[j]; }
#pragma unroll
  for (int off = 32; off > 0; off >>= 1) {
    s += __shfl_xor(s, off);
    s2 += __shfl_xor(s2, off);
  }
  const float mu = s * (1.f / 512.f);
  const float var = s2 * (1.f / 512.f) - mu * mu;
  const float inv = rsqrtf(var + 1e-5f);
  float4 w0 = *(const float4*)&lw[lane * 8];
  float4 w1 = *(const float4*)&lw[lane * 8 + 4];
  float4 b0 = *(const float4*)&lb[lane * 8];
  float4 b1 = *(const float4*)&lb[lane * 8 + 4];
  float4 o0 = make_float4((v[0] - mu) * inv * w0.x + b0.x, (v[1] - mu) * inv * w0.y + b0.y,
                          (v[2] - mu) * inv * w0.z + b0.z, (v[3] - mu) * inv * w0.w + b0.w);
  float4 o1 = make_float4((v[4] - mu) * inv * w1.x + b1.x, (v[5] - mu) * inv * w1.y + b1.y,
                          (v[6] - mu) * inv * w1.z + b1.z, (v[7] - mu) * inv * w1.w + b1.w);
  float* dst = out + (long)row * 512 + lane * 8;
  *(float4*)dst = o0;
  *(float4*)(dst + 4) = o1;
}

extern "C" void kernel_launch(void* const* d_in, const int* in_sizes, int n_in,
                              void* d_out, int out_size, void* d_ws, size_t ws_size,
                              hipStream_t stream) {
  const float* x = (const float*)d_in[0];
  const float* attn_bias = (const float*)d_in[1];
  const float* Wq = (const float*)d_in[2];
  const float* bq = (const float*)d_in[3];
  const float* Wk = (const float*)d_in[4];
  const float* bk = (const float*)d_in[5];
  const float* Wv = (const float*)d_in[6];
  const float* bv = (const float*)d_in[7];
  const float* Wp = (const float*)d_in[8];
  const float* bp = (const float*)d_in[9];
  const float* ln_w = (const float*)d_in[10];
  const float* ln_b = (const float*)d_in[11];
  const int* batch = (const int*)d_in[12];
  float* out = (float*)d_out;

  char* ws = (char*)d_ws;
  int* starts = (int*)ws;                        // 65 ints (512B reserved)
  short* Xbf = (short*)(ws + 512);               // NTOT x 512 bf16
  short* Wqb = Xbf + (long)NTOT * 512;
  short* Wkb = Wqb + 512 * 512;
  short* Wvb = Wkb + 512 * 512;
  short* Wpb = Wvb + 512 * 512;
  short* QKVbf = Wpb + 512 * 512;                // NTOT x 1536 bf16
  short* Obf = Xbf;                              // reuse: Xbf dead after QKV GEMM
  float* proj = (float*)QKVbf;                   // reuse: QKVbf dead after attention

  k_starts<<<(NTOT + 255) / 256, 256, 0, stream>>>(batch, starts);
  k_cvt<<<1537 + 4 * 128, 256, 0, stream>>>(x, Wq, Wk, Wv, Wp, Xbf, Wqb, Wkb, Wvb, Wpb);

  dim3 gq(12, (NTOT + 127) / 128);  // fused QKV: N = 1536 (n fastest), bf16 out
  k_gemm_mfma<true><<<gq, 256, 0, stream>>>(Xbf, Wqb, Wkb, Wvb, bq, bk, bv,
                                            nullptr, QKVbf, 1536, NTOT);

  dim3 ga(16, NB);  // (h, b)
  k_attn<<<ga, 256, 0, stream>>>(QKVbf, attn_bias, starts, Obf);

  dim3 gp(4, (NTOT + 127) / 128);  // proj: N = 512, residual fused, f32 out
  k_gemm_mfma<false><<<gp, 256, 0, stream>>>(Obf, Wpb, Wpb, Wpb, bp, bp, bp,
                                             x, proj, 512, NTOT);

  k_lnp<<<(NTOT + 3) / 4, 256, 0, stream>>>(proj, ln_w, ln_b, out);
}

// Round 10
// 85.396 us; speedup vs baseline: 1.2287x; 1.2287x over previous
//
#include <hip/hip_runtime.h>
#include <math.h>

#define NTOT 6148
#define NB 64
#define DM 512
#define SCALE_F 0.17677669529663687f

typedef __attribute__((ext_vector_type(8))) short bf16x8;
typedef __attribute__((ext_vector_type(4))) float f32x4;

__device__ __forceinline__ short f2bf(float f) {
  union { float f; unsigned u; } v; v.f = f;
  unsigned r = (v.u + 0x7fffu + ((v.u >> 16) & 1u)) >> 16;
  return (short)r;
}

__device__ __forceinline__ void gl_lds16(const void* g, void* l) {
  auto gp = (const __attribute__((address_space(1))) unsigned*)(unsigned long long)(uintptr_t)g;
  auto lp = (__attribute__((address_space(3))) unsigned*)(unsigned long long)(uintptr_t)l;
  __builtin_amdgcn_global_load_lds(gp, lp, 16, 0, 0);
}

// ---------------- starts from batch array ----------------
__global__ __launch_bounds__(256) void k_starts(const int* __restrict__ batch,
                                                int* __restrict__ starts) {
  int i = blockIdx.x * 256 + threadIdx.x;
  if (i >= NTOT) return;
  int b = batch[i];
  if (i == 0) starts[b] = 0;
  else if (batch[i - 1] != b) starts[b] = i;
  if (i == NTOT - 1) starts[NB] = NTOT;
}

// ---------------- f32 -> bf16 conversion (x + 4 weight matrices) ----------------
__global__ __launch_bounds__(256) void k_cvt(const float* __restrict__ x,
                                             const float* __restrict__ wq,
                                             const float* __restrict__ wk,
                                             const float* __restrict__ wv,
                                             const float* __restrict__ wp,
                                             short* __restrict__ xb,
                                             short* __restrict__ wqb,
                                             short* __restrict__ wkb,
                                             short* __restrict__ wvb,
                                             short* __restrict__ wpb) {
  const int bid = blockIdx.x;
  const float* s; short* d; long off;
  if (bid < 1537) {  // 1537*2048 == NTOT*512 exactly
    s = x; d = xb;
    off = ((long)bid * 256 + threadIdx.x) * 8;
  } else {
    int wi = (bid - 1537) >> 7;  // 128 blocks per 512x512 matrix
    s = (wi == 0) ? wq : (wi == 1) ? wk : (wi == 2) ? wv : wp;
    d = (wi == 0) ? wqb : (wi == 1) ? wkb : (wi == 2) ? wvb : wpb;
    off = ((long)((bid - 1537) & 127) * 256 + threadIdx.x) * 8;
  }
  float4 v0 = *(const float4*)(s + off);
  float4 v1 = *(const float4*)(s + off + 4);
  bf16x8 o;
  o[0] = f2bf(v0.x); o[1] = f2bf(v0.y); o[2] = f2bf(v0.z); o[3] = f2bf(v0.w);
  o[4] = f2bf(v1.x); o[5] = f2bf(v1.y); o[6] = f2bf(v1.z); o[7] = f2bf(v1.w);
  *(bf16x8*)(d + off) = o;
}

// ---------------- bf16 MFMA GEMM, 64xNT tile (grid-TLP oriented) ----------------
// C = A[M][512](bf16) @ W[N][512](bf16)^T + bias. BK=32, 4 waves (2x2 of 32xNT/2).
// Small tiles -> 3-6 blocks/CU resident; cross-block wave overlap hides drains.
template <int NT, bool BF16OUT>
__global__ __launch_bounds__(256) void k_gemm_mfma(
    const short* __restrict__ Abf,
    const short* __restrict__ W0, const short* __restrict__ W1, const short* __restrict__ W2,
    const float* __restrict__ b0, const float* __restrict__ b1, const float* __restrict__ b2,
    const float* __restrict__ resid, void* __restrict__ Cv, int ldc, int M) {
  constexpr int NF = NT / 32;  // n-frags per wave
  __shared__ __align__(16) short As[2][64][32];
  __shared__ __align__(16) short Bs[2][NT][32];
  const int tid = threadIdx.x;
  const int w = tid >> 6, l = tid & 63;
  const int m0 = blockIdx.y * 64;
  const int n0 = blockIdx.x * NT;
  const int sel = n0 >> 9;
  const short* Wt = (sel == 0) ? W0 : (sel == 1) ? W1 : W2;
  const float* bt = (sel == 0) ? b0 : (sel == 1) ? b1 : b2;
  const int nl0 = n0 & 511;
  const int wr = w >> 1, wc = w & 1;
  const int lr = l >> 2;        // 0..15: row within a 16-row (1KB) DMA chunk
  const int lc = (l & 3) * 8;   // short offset of this lane's 16B piece
  const int fr = l & 15, fs = (l >> 4) * 8;

  // global addresses for this wave's staging chunks
  const long gaA = (long)min(m0 + w * 16 + lr, M - 1) * 512 + lc;       // A: 16 rows/wave
  const long gaB0 = (long)(nl0 + ((NT == 128) ? w * 32 : w * 16) + lr) * 512 + lc;
  const long gaB1 = (long)(nl0 + w * 32 + 16 + lr) * 512 + lc;          // only NT=128

  f32x4 acc[2][NF];
#pragma unroll
  for (int m = 0; m < 2; m++)
#pragma unroll
    for (int n = 0; n < NF; n++) acc[m][n] = (f32x4){0.f, 0.f, 0.f, 0.f};

  auto stage = [&](int kt, int buf) {
    const int k0 = kt * 32;
    gl_lds16(Abf + gaA + k0, &As[buf][w * 16][0]);
    if (NT == 128) {
      gl_lds16(Wt + gaB0 + k0, &Bs[buf][w * 32][0]);
      gl_lds16(Wt + gaB1 + k0, &Bs[buf][w * 32 + 16][0]);
    } else {
      gl_lds16(Wt + gaB0 + k0, &Bs[buf][w * 16][0]);
    }
  };
  auto compute = [&](int buf) {
    bf16x8 af[2], bfr[NF];
#pragma unroll
    for (int m = 0; m < 2; m++) af[m] = *(const bf16x8*)&As[buf][wr * 32 + m * 16 + fr][fs];
#pragma unroll
    for (int n = 0; n < NF; n++)
      bfr[n] = *(const bf16x8*)&Bs[buf][wc * (NT / 2) + n * 16 + fr][fs];
#pragma unroll
    for (int m = 0; m < 2; m++)
#pragma unroll
      for (int n = 0; n < NF; n++)
        acc[m][n] = __builtin_amdgcn_mfma_f32_16x16x32_bf16(af[m], bfr[n], acc[m][n], 0, 0, 0);
  };

  stage(0, 0);
  __syncthreads();
  for (int step = 0; step < 16; step++) {
    if (step < 15) stage(step + 1, (step + 1) & 1);
    compute(step & 1);
    __syncthreads();  // drains prefetch (overlapped with other resident blocks)
  }

  // epilogue: C/D layout col=lane&15, row=(lane>>4)*4+j
  const int er = (l >> 4) * 4, ec = l & 15;
#pragma unroll
  for (int n = 0; n < NF; n++) {
    const int col = n0 + wc * (NT / 2) + n * 16 + ec;
    const float bv = bt[col & 511];
#pragma unroll
    for (int m = 0; m < 2; m++) {
      const int rowb = m0 + wr * 32 + m * 16 + er;
#pragma unroll
      for (int j = 0; j < 4; j++) {
        const int row = rowb + j;
        if (row < M) {
          float v = acc[m][n][j] + bv;
          if (resid) v += resid[(long)row * 512 + col];
          if (BF16OUT) ((short*)Cv)[(long)row * ldc + col] = f2bf(v);
          else ((float*)Cv)[(long)row * ldc + col] = v;
        }
      }
    }
  }
}

// ---------------- MFMA attention: one block per (h, b), 4 waves x 32 q-rows ----
// Bias panel DMA'd (global_load_lds, f32) into a per-wave LDS strip; softmax
// reads bias from LDS, then unnormalized bf16 P overwrites the same strip
// (reads of each m-half complete before its P writes; wave-local in-order LDS).
__global__ __launch_bounds__(256, 2) void k_attn(const short* __restrict__ QKVbf,
                                                 const float* __restrict__ bias,
                                                 const int* __restrict__ starts,
                                                 short* __restrict__ Obf) {
  __shared__ __align__(16) float BiasP[4][16][264];  // per-wave: 16 x (2 rows x 128 + 8 pad)
  __shared__ __align__(16) short Vtb[32][136];       // V transposed (rows = d)
  const int h = blockIdx.x, b = blockIdx.y;
  const int s0 = starts[b], cnt = starts[b + 1] - s0;
  const int tid = threadIdx.x, l = tid & 63, w = tid >> 6;
  const int wq0 = w * 32;
  const int lg = l >> 4, lk = l & 15, fs = lg * 8;
  const bool active = wq0 < cnt;
  short* Pw = (short*)&BiasP[w][0][0];  // P rows: 32 x 136 shorts, aliases bias strip

  // ---- issue V reg loads (own 32 k-rows, clamped => finite) ----
  const int u = l >> 2, c = (l & 3) * 8;
  const short* vbase = QKVbf + 1024 + h * 32 + c;
  const bf16x8 v0 = *(const bf16x8*)(vbase + (long)(s0 + min(wq0 + u, cnt - 1)) * 1536);
  const bf16x8 v1 = *(const bf16x8*)(vbase + (long)(s0 + min(wq0 + u + 16, cnt - 1)) * 1536);

  // ---- issue 16x 1KB bias DMA (fire-and-forget, no VGPRs) ----
  const float* bbase = bias + ((long)(b * 16 + h) << 14);
  if (active) {
    const float* bsrc = bbase + (long)wq0 * 128 + l * 4;  // lane's 16B within each 1KB chunk
#pragma unroll
    for (int t = 0; t < 16; t++)
      gl_lds16(bsrc + t * 256, &BiasP[w][t][0]);
  }

  // ---- issue Q/K fragment reg loads ----
  bf16x8 aq[2], bk[8];
  if (active) {
    const short* qbase = QKVbf + h * 32 + fs;
#pragma unroll
    for (int m = 0; m < 2; m++)
      aq[m] = *(const bf16x8*)(qbase + (long)(s0 + min(wq0 + m * 16 + lk, cnt - 1)) * 1536);
#pragma unroll
    for (int n = 0; n < 8; n++)
      bk[n] = *(const bf16x8*)(qbase + 512 + (long)(s0 + min(n * 16 + lk, cnt - 1)) * 1536);
  }

  // ---- V scatter-transpose into LDS (rows >= cnt finite, killed by P==0) ----
#pragma unroll
  for (int i = 0; i < 8; i++) Vtb[c + i][wq0 + u] = v0[i];
#pragma unroll
  for (int i = 0; i < 8; i++) Vtb[c + i][wq0 + u + 16] = v1[i];

  f32x4 S[2][8];
  float invs[2][4];
  if (active) {
    // ---- S = Q K^T (16 MFMA) ----
#pragma unroll
    for (int n = 0; n < 8; n++)
#pragma unroll
      for (int m = 0; m < 2; m++)
        S[m][n] = __builtin_amdgcn_mfma_f32_16x16x32_bf16(aq[m], bk[n],
                                                          (f32x4){0.f, 0.f, 0.f, 0.f}, 0, 0, 0);
    // DMA has no dest reg: explicitly drain before reading the bias strip
    asm volatile("s_waitcnt vmcnt(0)" ::: "memory");
    __builtin_amdgcn_sched_barrier(0);

    // ---- bias(LDS,f32) + scale + mask + softmax; unnormalized P -> strip ----
#pragma unroll
    for (int m = 0; m < 2; m++) {
      const int rb = m * 16 + lg * 4;  // local q row base
#pragma unroll
      for (int n = 0; n < 8; n++) {
        const int k = n * 16 + lk;
        const bool kok = k < cnt;
#pragma unroll
        for (int j = 0; j < 4; j++) {
          const int r = rb + j;
          const float sv = S[m][n][j] * SCALE_F + BiasP[w][r >> 1][(r & 1) * 128 + k];
          S[m][n][j] = kok ? sv : -1e30f;
        }
      }
#pragma unroll
      for (int j = 0; j < 4; j++) {
        float mx = S[m][0][j];
#pragma unroll
        for (int n = 1; n < 8; n++) mx = fmaxf(mx, S[m][n][j]);
        mx = fmaxf(mx, __shfl_xor(mx, 1));
        mx = fmaxf(mx, __shfl_xor(mx, 2));
        mx = fmaxf(mx, __shfl_xor(mx, 4));
        mx = fmaxf(mx, __shfl_xor(mx, 8));
        float sum = 0.f;
#pragma unroll
        for (int n = 0; n < 8; n++) {
          const float p = __expf(S[m][n][j] - mx);
          S[m][n][j] = p;
          sum += p;
        }
        sum += __shfl_xor(sum, 1);
        sum += __shfl_xor(sum, 2);
        sum += __shfl_xor(sum, 4);
        sum += __shfl_xor(sum, 8);
        invs[m][j] = 1.f / sum;
        const int r = rb + j;
#pragma unroll
        for (int n = 0; n < 8; n++) Pw[r * 136 + n * 16 + lk] = f2bf(S[m][n][j]);
      }
    }
  }

  __syncthreads();  // V (cross-wave) visibility; P/bias strips are wave-local
  if (!active) return;

  // ---- O = P V (16 MFMA), same-wave LDS RAW ----
  f32x4 O[2][2];
#pragma unroll
  for (int m = 0; m < 2; m++)
#pragma unroll
    for (int dt = 0; dt < 2; dt++) O[m][dt] = (f32x4){0.f, 0.f, 0.f, 0.f};
#pragma unroll
  for (int kc = 0; kc < 4; kc++) {
    bf16x8 pa[2], vb[2];
#pragma unroll
    for (int m = 0; m < 2; m++)
      pa[m] = *(const bf16x8*)&Pw[(m * 16 + lk) * 136 + kc * 32 + fs];
#pragma unroll
    for (int dt = 0; dt < 2; dt++) vb[dt] = *(const bf16x8*)&Vtb[dt * 16 + lk][kc * 32 + fs];
#pragma unroll
    for (int m = 0; m < 2; m++)
#pragma unroll
      for (int dt = 0; dt < 2; dt++)
        O[m][dt] = __builtin_amdgcn_mfma_f32_16x16x32_bf16(pa[m], vb[dt], O[m][dt], 0, 0, 0);
  }
  // ---- store O (bf16), fold in 1/sum ----
#pragma unroll
  for (int m = 0; m < 2; m++) {
    const int qb0 = wq0 + m * 16 + lg * 4;
#pragma unroll
    for (int j = 0; j < 4; j++) {
      if (qb0 + j < cnt) {
        short* orow = Obf + (long)(s0 + qb0 + j) * 512 + h * 32;
#pragma unroll
        for (int dt = 0; dt < 2; dt++)
          orow[dt * 16 + lk] = f2bf(O[m][dt][j] * invs[m][j]);
      }
    }
  }
}

// ---------------- LayerNorm (residual pre-added), one wave per row ----------------
__global__ __launch_bounds__(256) void k_lnp(const float* __restrict__ pre,
                                             const float* __restrict__ lw,
                                             const float* __restrict__ lb,
                                             float* __restrict__ out) {
  const int row = blockIdx.x * 4 + (threadIdx.x >> 6);
  if (row >= NTOT) return;
  const int lane = threadIdx.x & 63;
  const float* pr = pre + (long)row * 512 + lane * 8;
  float4 p0 = *(const float4*)pr;
  float4 p1 = *(const float4*)(pr + 4);
  float v[8] = {p0.x, p0.y, p0.z, p0.w, p1.x, p1.y, p1.z, p1.w};
  float s = 0.f, s2 = 0.f;
#pragma unroll
  for (int j = 0; j < 8; j++) { s += v[j]; s2 += v[j] * v[j]; }
#pragma unroll
  for (int off = 32; off > 0; off >>= 1) {
    s += __shfl_xor(s, off);
    s2 += __shfl_xor(s2, off);
  }
  const float mu = s * (1.f / 512.f);
  const float var = s2 * (1.f / 512.f) - mu * mu;
  const float inv = rsqrtf(var + 1e-5f);
  float4 w0 = *(const float4*)&lw[lane * 8];
  float4 w1 = *(const float4*)&lw[lane * 8 + 4];
  float4 b0 = *(const float4*)&lb[lane * 8];
  float4 b1 = *(const float4*)&lb[lane * 8 + 4];
  float4 o0 = make_float4((v[0] - mu) * inv * w0.x + b0.x, (v[1] - mu) * inv * w0.y + b0.y,
                          (v[2] - mu) * inv * w0.z + b0.z, (v[3] - mu) * inv * w0.w + b0.w);
  float4 o1 = make_float4((v[4] - mu) * inv * w1.x + b1.x, (v[5] - mu) * inv * w1.y + b1.y,
                          (v[6] - mu) * inv * w1.z + b1.z, (v[7] - mu) * inv * w1.w + b1.w);
  float* dst = out + (long)row * 512 + lane * 8;
  *(float4*)dst = o0;
  *(float4*)(dst + 4) = o1;
}

extern "C" void kernel_launch(void* const* d_in, const int* in_sizes, int n_in,
                              void* d_out, int out_size, void* d_ws, size_t ws_size,
                              hipStream_t stream) {
  const float* x = (const float*)d_in[0];
  const float* attn_bias = (const float*)d_in[1];
  const float* Wq = (const float*)d_in[2];
  const float* bq = (const float*)d_in[3];
  const float* Wk = (const float*)d_in[4];
  const float* bk = (const float*)d_in[5];
  const float* Wv = (const float*)d_in[6];
  const float* bv = (const float*)d_in[7];
  const float* Wp = (const float*)d_in[8];
  const float* bp = (const float*)d_in[9];
  const float* ln_w = (const float*)d_in[10];
  const float* ln_b = (const float*)d_in[11];
  const int* batch = (const int*)d_in[12];
  float* out = (float*)d_out;

  char* ws = (char*)d_ws;
  int* starts = (int*)ws;                        // 65 ints (512B reserved)
  short* Xbf = (short*)(ws + 512);               // NTOT x 512 bf16
  short* Wqb = Xbf + (long)NTOT * 512;
  short* Wkb = Wqb + 512 * 512;
  short* Wvb = Wkb + 512 * 512;
  short* Wpb = Wvb + 512 * 512;
  short* QKVbf = Wpb + 512 * 512;                // NTOT x 1536 bf16
  short* Obf = Xbf;                              // reuse: Xbf dead after QKV GEMM
  float* proj = (float*)QKVbf;                   // reuse: QKVbf dead after attention

  k_starts<<<(NTOT + 255) / 256, 256, 0, stream>>>(batch, starts);
  k_cvt<<<1537 + 4 * 128, 256, 0, stream>>>(x, Wq, Wk, Wv, Wp, Xbf, Wqb, Wkb, Wvb, Wpb);

  dim3 gq(12, (NTOT + 63) / 64);  // fused QKV: N = 1536, 64x128 tiles, bf16 out
  k_gemm_mfma<128, true><<<gq, 256, 0, stream>>>(Xbf, Wqb, Wkb, Wvb, bq, bk, bv,
                                                 nullptr, QKVbf, 1536, NTOT);

  dim3 ga(16, NB);  // (h, b)
  k_attn<<<ga, 256, 0, stream>>>(QKVbf, attn_bias, starts, Obf);

  dim3 gp(8, (NTOT + 63) / 64);  // proj: N = 512, 64x64 tiles, residual fused, f32 out
  k_gemm_mfma<64, false><<<gp, 256, 0, stream>>>(Obf, Wpb, Wpb, Wpb, bp, bp, bp,
                                                 x, proj, 512, NTOT);

  k_lnp<<<(NTOT + 3) / 4, 256, 0, stream>>>(proj, ln_w, ln_b, out);
}

// Round 11
// 83.466 us; speedup vs baseline: 1.2571x; 1.0231x over previous
//
#include <hip/hip_runtime.h>
#include <math.h>

#define NTOT 6148
#define NB 64
#define DM 512
#define SCALE_F 0.17677669529663687f

typedef __attribute__((ext_vector_type(8))) short bf16x8;
typedef __attribute__((ext_vector_type(4))) float f32x4;

__device__ __forceinline__ short f2bf(float f) {
  union { float f; unsigned u; } v; v.f = f;
  unsigned r = (v.u + 0x7fffu + ((v.u >> 16) & 1u)) >> 16;
  return (short)r;
}

__device__ __forceinline__ void gl_lds16(const void* g, void* l) {
  auto gp = (const __attribute__((address_space(1))) unsigned*)(unsigned long long)(uintptr_t)g;
  auto lp = (__attribute__((address_space(3))) unsigned*)(unsigned long long)(uintptr_t)l;
  __builtin_amdgcn_global_load_lds(gp, lp, 16, 0, 0);
}

// ---------------- starts from batch array ----------------
__global__ __launch_bounds__(256) void k_starts(const int* __restrict__ batch,
                                                int* __restrict__ starts) {
  int i = blockIdx.x * 256 + threadIdx.x;
  if (i >= NTOT) return;
  int b = batch[i];
  if (i == 0) starts[b] = 0;
  else if (batch[i - 1] != b) starts[b] = i;
  if (i == NTOT - 1) starts[NB] = NTOT;
}

// ---------------- f32 -> bf16 conversion (x + 4 weight matrices) ----------------
__global__ __launch_bounds__(256) void k_cvt(const float* __restrict__ x,
                                             const float* __restrict__ wq,
                                             const float* __restrict__ wk,
                                             const float* __restrict__ wv,
                                             const float* __restrict__ wp,
                                             short* __restrict__ xb,
                                             short* __restrict__ wqb,
                                             short* __restrict__ wkb,
                                             short* __restrict__ wvb,
                                             short* __restrict__ wpb) {
  const int bid = blockIdx.x;
  const float* s; short* d; long off;
  if (bid < 1537) {  // 1537*2048 == NTOT*512 exactly
    s = x; d = xb;
    off = ((long)bid * 256 + threadIdx.x) * 8;
  } else {
    int wi = (bid - 1537) >> 7;  // 128 blocks per 512x512 matrix
    s = (wi == 0) ? wq : (wi == 1) ? wk : (wi == 2) ? wv : wp;
    d = (wi == 0) ? wqb : (wi == 1) ? wkb : (wi == 2) ? wvb : wpb;
    off = ((long)((bid - 1537) & 127) * 256 + threadIdx.x) * 8;
  }
  float4 v0 = *(const float4*)(s + off);
  float4 v1 = *(const float4*)(s + off + 4);
  bf16x8 o;
  o[0] = f2bf(v0.x); o[1] = f2bf(v0.y); o[2] = f2bf(v0.z); o[3] = f2bf(v0.w);
  o[4] = f2bf(v1.x); o[5] = f2bf(v1.y); o[6] = f2bf(v1.z); o[7] = f2bf(v1.w);
  *(bf16x8*)(d + off) = o;
}

// ---------------- bf16 MFMA GEMM, 64xNT tile (grid-TLP oriented) ----------------
// C = A[M][512](bf16) @ W[N][512](bf16)^T + bias. BK=32, 4 waves (2x2 of 32xNT/2).
// Small tiles -> 3-6 blocks/CU resident; cross-block wave overlap hides drains.
template <int NT, bool BF16OUT>
__global__ __launch_bounds__(256) void k_gemm_mfma(
    const short* __restrict__ Abf,
    const short* __restrict__ W0, const short* __restrict__ W1, const short* __restrict__ W2,
    const float* __restrict__ b0, const float* __restrict__ b1, const float* __restrict__ b2,
    const float* __restrict__ resid, void* __restrict__ Cv, int ldc, int M) {
  constexpr int NF = NT / 32;  // n-frags per wave
  __shared__ __align__(16) short As[2][64][32];
  __shared__ __align__(16) short Bs[2][NT][32];
  const int tid = threadIdx.x;
  const int w = tid >> 6, l = tid & 63;
  const int m0 = blockIdx.y * 64;
  const int n0 = blockIdx.x * NT;
  const int sel = n0 >> 9;
  const short* Wt = (sel == 0) ? W0 : (sel == 1) ? W1 : W2;
  const float* bt = (sel == 0) ? b0 : (sel == 1) ? b1 : b2;
  const int nl0 = n0 & 511;
  const int wr = w >> 1, wc = w & 1;
  const int lr = l >> 2;        // 0..15: row within a 16-row (1KB) DMA chunk
  const int lc = (l & 3) * 8;   // short offset of this lane's 16B piece
  const int fr = l & 15, fs = (l >> 4) * 8;

  // global addresses for this wave's staging chunks
  const long gaA = (long)min(m0 + w * 16 + lr, M - 1) * 512 + lc;       // A: 16 rows/wave
  const long gaB0 = (long)(nl0 + ((NT == 128) ? w * 32 : w * 16) + lr) * 512 + lc;
  const long gaB1 = (long)(nl0 + w * 32 + 16 + lr) * 512 + lc;          // only NT=128

  f32x4 acc[2][NF];
#pragma unroll
  for (int m = 0; m < 2; m++)
#pragma unroll
    for (int n = 0; n < NF; n++) acc[m][n] = (f32x4){0.f, 0.f, 0.f, 0.f};

  auto stage = [&](int kt, int buf) {
    const int k0 = kt * 32;
    gl_lds16(Abf + gaA + k0, &As[buf][w * 16][0]);
    if (NT == 128) {
      gl_lds16(Wt + gaB0 + k0, &Bs[buf][w * 32][0]);
      gl_lds16(Wt + gaB1 + k0, &Bs[buf][w * 32 + 16][0]);
    } else {
      gl_lds16(Wt + gaB0 + k0, &Bs[buf][w * 16][0]);
    }
  };
  auto compute = [&](int buf) {
    bf16x8 af[2], bfr[NF];
#pragma unroll
    for (int m = 0; m < 2; m++) af[m] = *(const bf16x8*)&As[buf][wr * 32 + m * 16 + fr][fs];
#pragma unroll
    for (int n = 0; n < NF; n++)
      bfr[n] = *(const bf16x8*)&Bs[buf][wc * (NT / 2) + n * 16 + fr][fs];
#pragma unroll
    for (int m = 0; m < 2; m++)
#pragma unroll
      for (int n = 0; n < NF; n++)
        acc[m][n] = __builtin_amdgcn_mfma_f32_16x16x32_bf16(af[m], bfr[n], acc[m][n], 0, 0, 0);
  };

  stage(0, 0);
  __syncthreads();
  for (int step = 0; step < 16; step++) {
    if (step < 15) stage(step + 1, (step + 1) & 1);
    compute(step & 1);
    __syncthreads();  // drains prefetch (overlapped with other resident blocks)
  }

  // epilogue: C/D layout col=lane&15, row=(lane>>4)*4+j
  const int er = (l >> 4) * 4, ec = l & 15;
#pragma unroll
  for (int n = 0; n < NF; n++) {
    const int col = n0 + wc * (NT / 2) + n * 16 + ec;
    const float bv = bt[col & 511];
#pragma unroll
    for (int m = 0; m < 2; m++) {
      const int rowb = m0 + wr * 32 + m * 16 + er;
#pragma unroll
      for (int j = 0; j < 4; j++) {
        const int row = rowb + j;
        if (row < M) {
          float v = acc[m][n][j] + bv;
          if (resid) v += resid[(long)row * 512 + col];
          if (BF16OUT) ((short*)Cv)[(long)row * ldc + col] = f2bf(v);
          else ((float*)Cv)[(long)row * ldc + col] = v;
        }
      }
    }
  }
}

// ---------------- MFMA attention: one block per (h, b), 8 waves x 16 q-rows ----
// Bias panel DMA'd (global_load_lds, f32) at kernel ENTRY (independent of
// starts) into a per-wave LDS strip; softmax reads bias from LDS, then
// unnormalized bf16 P overwrites the same strip (all bias reads of the strip
// precede its P writes in program order; per-wave LDS is in-order).
__global__ __launch_bounds__(512, 4) void k_attn(const short* __restrict__ QKVbf,
                                                 const float* __restrict__ bias,
                                                 const int* __restrict__ starts,
                                                 short* __restrict__ Obf) {
  __shared__ __align__(16) float BiasP[8][8][264];  // per-wave: 8 x (2 rows x 128 + 8 pad)
  __shared__ __align__(16) short Vtb[32][136];      // V transposed (rows = d)
  const int h = blockIdx.x, b = blockIdx.y;
  const int tid = threadIdx.x, l = tid & 63, w = tid >> 6;  // w = 0..7
  const int wq0 = w * 16;
  const int lg = l >> 4, lk = l & 15, fs = lg * 8;
  short* Pw = (short*)&BiasP[w][0][0];  // P rows: 16 x 136 shorts, aliases bias strip

  // ---- bias DMA FIRST: independent of starts, 8x 1KB per wave, no VGPRs ----
  {
    const float* bsrc = bias + ((long)(b * 16 + h) << 14) + (long)wq0 * 128 + l * 4;
#pragma unroll
    for (int t = 0; t < 8; t++)
      gl_lds16(bsrc + t * 256, &BiasP[w][t][0]);
  }

  const int s0 = starts[b], cnt = starts[b + 1] - s0;
  const bool active = wq0 < cnt;

  // ---- V reg load (wave's own 16 k-rows, clamped => finite) ----
  const int u = l >> 2, c = (l & 3) * 8;
  const short* vbase = QKVbf + 1024 + h * 32 + c;
  const bf16x8 v0 = *(const bf16x8*)(vbase + (long)(s0 + min(wq0 + u, cnt - 1)) * 1536);

  // ---- Q/K fragment reg loads ----
  bf16x8 aq, bk[8];
  if (active) {
    const short* qbase = QKVbf + h * 32 + fs;
    aq = *(const bf16x8*)(qbase + (long)(s0 + min(wq0 + lk, cnt - 1)) * 1536);
#pragma unroll
    for (int n = 0; n < 8; n++)
      bk[n] = *(const bf16x8*)(qbase + 512 + (long)(s0 + min(n * 16 + lk, cnt - 1)) * 1536);
  }

  // ---- V scatter-transpose into LDS (rows >= cnt finite, killed by P==0) ----
#pragma unroll
  for (int i = 0; i < 8; i++) Vtb[c + i][wq0 + u] = v0[i];

  // drain all outstanding VMEM (incl. LDS-DMA with no dest reg) before any
  // wave reads its bias strip or exits across the barrier
  asm volatile("s_waitcnt vmcnt(0)" ::: "memory");
  __builtin_amdgcn_sched_barrier(0);

  f32x4 S[8];
  float invs[4];
  if (active) {
    // ---- S = Q K^T (8 MFMA) ----
#pragma unroll
    for (int n = 0; n < 8; n++)
      S[n] = __builtin_amdgcn_mfma_f32_16x16x32_bf16(aq, bk[n],
                                                     (f32x4){0.f, 0.f, 0.f, 0.f}, 0, 0, 0);
    // ---- bias(LDS,f32) + scale + mask ----
#pragma unroll
    for (int n = 0; n < 8; n++) {
      const int k = n * 16 + lk;
      const bool kok = k < cnt;
#pragma unroll
      for (int j = 0; j < 4; j++) {
        const int r = lg * 4 + j;  // local q row 0..15
        const float sv = S[n][j] * SCALE_F + BiasP[w][r >> 1][(r & 1) * 128 + k];
        S[n][j] = kok ? sv : -1e30f;
      }
    }
    // ---- softmax (16-lane k-reduce); unnormalized bf16 P -> own strip ----
#pragma unroll
    for (int j = 0; j < 4; j++) {
      float mx = S[0][j];
#pragma unroll
      for (int n = 1; n < 8; n++) mx = fmaxf(mx, S[n][j]);
      mx = fmaxf(mx, __shfl_xor(mx, 1));
      mx = fmaxf(mx, __shfl_xor(mx, 2));
      mx = fmaxf(mx, __shfl_xor(mx, 4));
      mx = fmaxf(mx, __shfl_xor(mx, 8));
      float sum = 0.f;
#pragma unroll
      for (int n = 0; n < 8; n++) {
        const float p = __expf(S[n][j] - mx);
        S[n][j] = p;
        sum += p;
      }
      sum += __shfl_xor(sum, 1);
      sum += __shfl_xor(sum, 2);
      sum += __shfl_xor(sum, 4);
      sum += __shfl_xor(sum, 8);
      invs[j] = 1.f / sum;
      const int r = lg * 4 + j;
#pragma unroll
      for (int n = 0; n < 8; n++) Pw[r * 136 + n * 16 + lk] = f2bf(S[n][j]);
    }
  }

  __syncthreads();  // V (cross-wave) visibility; P/bias strips are wave-local
  if (!active) return;

  // ---- O = P V (8 MFMA), same-wave LDS RAW ----
  f32x4 O[2];
#pragma unroll
  for (int dt = 0; dt < 2; dt++) O[dt] = (f32x4){0.f, 0.f, 0.f, 0.f};
#pragma unroll
  for (int kc = 0; kc < 4; kc++) {
    const bf16x8 pa = *(const bf16x8*)&Pw[lk * 136 + kc * 32 + fs];
#pragma unroll
    for (int dt = 0; dt < 2; dt++) {
      const bf16x8 vb = *(const bf16x8*)&Vtb[dt * 16 + lk][kc * 32 + fs];
      O[dt] = __builtin_amdgcn_mfma_f32_16x16x32_bf16(pa, vb, O[dt], 0, 0, 0);
    }
  }
  // ---- store O (bf16), fold in 1/sum ----
#pragma unroll
  for (int j = 0; j < 4; j++) {
    const int q = wq0 + lg * 4 + j;
    if (q < cnt) {
      short* orow = Obf + (long)(s0 + q) * 512 + h * 32;
#pragma unroll
      for (int dt = 0; dt < 2; dt++)
        orow[dt * 16 + lk] = f2bf(O[dt][j] * invs[j]);
    }
  }
}

// ---------------- LayerNorm (residual pre-added), one wave per row ----------------
__global__ __launch_bounds__(256) void k_lnp(const float* __restrict__ pre,
                                             const float* __restrict__ lw,
                                             const float* __restrict__ lb,
                                             float* __restrict__ out) {
  const int row = blockIdx.x * 4 + (threadIdx.x >> 6);
  if (row >= NTOT) return;
  const int lane = threadIdx.x & 63;
  const float* pr = pre + (long)row * 512 + lane * 8;
  float4 p0 = *(const float4*)pr;
  float4 p1 = *(const float4*)(pr + 4);
  float v[8] = {p0.x, p0.y, p0.z, p0.w, p1.x, p1.y, p1.z, p1.w};
  float s = 0.f, s2 = 0.f;
#pragma unroll
  for (int j = 0; j < 8; j++) { s += v[j]; s2 += v[j] * v[j]; }
#pragma unroll
  for (int off = 32; off > 0; off >>= 1) {
    s += __shfl_xor(s, off);
    s2 += __shfl_xor(s2, off);
  }
  const float mu = s * (1.f / 512.f);
  const float var = s2 * (1.f / 512.f) - mu * mu;
  const float inv = rsqrtf(var + 1e-5f);
  float4 w0 = *(const float4*)&lw[lane * 8];
  float4 w1 = *(const float4*)&lw[lane * 8 + 4];
  float4 b0 = *(const float4*)&lb[lane * 8];
  float4 b1 = *(const float4*)&lb[lane * 8 + 4];
  float4 o0 = make_float4((v[0] - mu) * inv * w0.x + b0.x, (v[1] - mu) * inv * w0.y + b0.y,
                          (v[2] - mu) * inv * w0.z + b0.z, (v[3] - mu) * inv * w0.w + b0.w);
  float4 o1 = make_float4((v[4] - mu) * inv * w1.x + b1.x, (v[5] - mu) * inv * w1.y + b1.y,
                          (v[6] - mu) * inv * w1.z + b1.z, (v[7] - mu) * inv * w1.w + b1.w);
  float* dst = out + (long)row * 512 + lane * 8;
  *(float4*)dst = o0;
  *(float4*)(dst + 4) = o1;
}

extern "C" void kernel_launch(void* const* d_in, const int* in_sizes, int n_in,
                              void* d_out, int out_size, void* d_ws, size_t ws_size,
                              hipStream_t stream) {
  const float* x = (const float*)d_in[0];
  const float* attn_bias = (const float*)d_in[1];
  const float* Wq = (const float*)d_in[2];
  const float* bq = (const float*)d_in[3];
  const float* Wk = (const float*)d_in[4];
  const float* bk = (const float*)d_in[5];
  const float* Wv = (const float*)d_in[6];
  const float* bv = (const float*)d_in[7];
  const float* Wp = (const float*)d_in[8];
  const float* bp = (const float*)d_in[9];
  const float* ln_w = (const float*)d_in[10];
  const float* ln_b = (const float*)d_in[11];
  const int* batch = (const int*)d_in[12];
  float* out = (float*)d_out;

  char* ws = (char*)d_ws;
  int* starts = (int*)ws;                        // 65 ints (512B reserved)
  short* Xbf = (short*)(ws + 512);               // NTOT x 512 bf16
  short* Wqb = Xbf + (long)NTOT * 512;
  short* Wkb = Wqb + 512 * 512;
  short* Wvb = Wkb + 512 * 512;
  short* Wpb = Wvb + 512 * 512;
  short* QKVbf = Wpb + 512 * 512;                // NTOT x 1536 bf16
  short* Obf = Xbf;                              // reuse: Xbf dead after QKV GEMM
  float* proj = (float*)QKVbf;                   // reuse: QKVbf dead after attention

  k_starts<<<(NTOT + 255) / 256, 256, 0, stream>>>(batch, starts);
  k_cvt<<<1537 + 4 * 128, 256, 0, stream>>>(x, Wq, Wk, Wv, Wp, Xbf, Wqb, Wkb, Wvb, Wpb);

  dim3 gq(12, (NTOT + 63) / 64);  // fused QKV: N = 1536, 64x128 tiles, bf16 out
  k_gemm_mfma<128, true><<<gq, 256, 0, stream>>>(Xbf, Wqb, Wkb, Wvb, bq, bk, bv,
                                                 nullptr, QKVbf, 1536, NTOT);

  dim3 ga(16, NB);  // (h, b), 8 waves x 16 q-rows
  k_attn<<<ga, 512, 0, stream>>>(QKVbf, attn_bias, starts, Obf);

  dim3 gp(8, (NTOT + 63) / 64);  // proj: N = 512, 64x64 tiles, residual fused, f32 out
  k_gemm_mfma<64, false><<<gp, 256, 0, stream>>>(Obf, Wpb, Wpb, Wpb, bp, bp, bp,
                                                 x, proj, 512, NTOT);

  k_lnp<<<(NTOT + 3) / 4, 256, 0, stream>>>(proj, ln_w, ln_b, out);
}

// Round 12
// 81.467 us; speedup vs baseline: 1.2879x; 1.0245x over previous
//
#include <hip/hip_runtime.h>
#include <math.h>

#define NTOT 6148
#define NB 64
#define DM 512
#define SCALE_F 0.17677669529663687f

typedef __attribute__((ext_vector_type(8))) short bf16x8;
typedef __attribute__((ext_vector_type(4))) float f32x4;

__device__ __forceinline__ short f2bf(float f) {
  union { float f; unsigned u; } v; v.f = f;
  unsigned r = (v.u + 0x7fffu + ((v.u >> 16) & 1u)) >> 16;
  return (short)r;
}

__device__ __forceinline__ void gl_lds16(const void* g, void* l) {
  auto gp = (const __attribute__((address_space(1))) unsigned*)(unsigned long long)(uintptr_t)g;
  auto lp = (__attribute__((address_space(3))) unsigned*)(unsigned long long)(uintptr_t)l;
  __builtin_amdgcn_global_load_lds(gp, lp, 16, 0, 0);
}

// ---------------- starts from batch array ----------------
__global__ __launch_bounds__(256) void k_starts(const int* __restrict__ batch,
                                                int* __restrict__ starts) {
  int i = blockIdx.x * 256 + threadIdx.x;
  if (i >= NTOT) return;
  int b = batch[i];
  if (i == 0) starts[b] = 0;
  else if (batch[i - 1] != b) starts[b] = i;
  if (i == NTOT - 1) starts[NB] = NTOT;
}

// ---------------- f32 -> bf16 conversion (x + 4 weight matrices) ----------------
__global__ __launch_bounds__(256) void k_cvt(const float* __restrict__ x,
                                             const float* __restrict__ wq,
                                             const float* __restrict__ wk,
                                             const float* __restrict__ wv,
                                             const float* __restrict__ wp,
                                             short* __restrict__ xb,
                                             short* __restrict__ wqb,
                                             short* __restrict__ wkb,
                                             short* __restrict__ wvb,
                                             short* __restrict__ wpb) {
  const int bid = blockIdx.x;
  const float* s; short* d; long off;
  if (bid < 1537) {  // 1537*2048 == NTOT*512 exactly
    s = x; d = xb;
    off = ((long)bid * 256 + threadIdx.x) * 8;
  } else {
    int wi = (bid - 1537) >> 7;  // 128 blocks per 512x512 matrix
    s = (wi == 0) ? wq : (wi == 1) ? wk : (wi == 2) ? wv : wp;
    d = (wi == 0) ? wqb : (wi == 1) ? wkb : (wi == 2) ? wvb : wpb;
    off = ((long)((bid - 1537) & 127) * 256 + threadIdx.x) * 8;
  }
  float4 v0 = *(const float4*)(s + off);
  float4 v1 = *(const float4*)(s + off + 4);
  bf16x8 o;
  o[0] = f2bf(v0.x); o[1] = f2bf(v0.y); o[2] = f2bf(v0.z); o[3] = f2bf(v0.w);
  o[4] = f2bf(v1.x); o[5] = f2bf(v1.y); o[6] = f2bf(v1.z); o[7] = f2bf(v1.w);
  *(bf16x8*)(d + off) = o;
}

// ---------------- bf16 MFMA GEMM, 64xNT tile (grid-TLP oriented) ----------------
// C = A[M][512](bf16) @ W[N][512](bf16)^T + bias. BK=32, 4 waves (2x2 of 32xNT/2).
template <int NT, bool BF16OUT>
__global__ __launch_bounds__(256) void k_gemm_mfma(
    const short* __restrict__ Abf,
    const short* __restrict__ W0, const short* __restrict__ W1, const short* __restrict__ W2,
    const float* __restrict__ b0, const float* __restrict__ b1, const float* __restrict__ b2,
    const float* __restrict__ resid, void* __restrict__ Cv, int ldc, int M) {
  constexpr int NF = NT / 32;  // n-frags per wave
  __shared__ __align__(16) short As[2][64][32];
  __shared__ __align__(16) short Bs[2][NT][32];
  const int tid = threadIdx.x;
  const int w = tid >> 6, l = tid & 63;
  const int m0 = blockIdx.y * 64;
  const int n0 = blockIdx.x * NT;
  const int sel = n0 >> 9;
  const short* Wt = (sel == 0) ? W0 : (sel == 1) ? W1 : W2;
  const float* bt = (sel == 0) ? b0 : (sel == 1) ? b1 : b2;
  const int nl0 = n0 & 511;
  const int wr = w >> 1, wc = w & 1;
  const int lr = l >> 2;        // 0..15: row within a 16-row (1KB) DMA chunk
  const int lc = (l & 3) * 8;   // short offset of this lane's 16B piece
  const int fr = l & 15, fs = (l >> 4) * 8;

  const long gaA = (long)min(m0 + w * 16 + lr, M - 1) * 512 + lc;       // A: 16 rows/wave
  const long gaB0 = (long)(nl0 + ((NT == 128) ? w * 32 : w * 16) + lr) * 512 + lc;
  const long gaB1 = (long)(nl0 + w * 32 + 16 + lr) * 512 + lc;          // only NT=128

  f32x4 acc[2][NF];
#pragma unroll
  for (int m = 0; m < 2; m++)
#pragma unroll
    for (int n = 0; n < NF; n++) acc[m][n] = (f32x4){0.f, 0.f, 0.f, 0.f};

  auto stage = [&](int kt, int buf) {
    const int k0 = kt * 32;
    gl_lds16(Abf + gaA + k0, &As[buf][w * 16][0]);
    if (NT == 128) {
      gl_lds16(Wt + gaB0 + k0, &Bs[buf][w * 32][0]);
      gl_lds16(Wt + gaB1 + k0, &Bs[buf][w * 32 + 16][0]);
    } else {
      gl_lds16(Wt + gaB0 + k0, &Bs[buf][w * 16][0]);
    }
  };
  auto compute = [&](int buf) {
    bf16x8 af[2], bfr[NF];
#pragma unroll
    for (int m = 0; m < 2; m++) af[m] = *(const bf16x8*)&As[buf][wr * 32 + m * 16 + fr][fs];
#pragma unroll
    for (int n = 0; n < NF; n++)
      bfr[n] = *(const bf16x8*)&Bs[buf][wc * (NT / 2) + n * 16 + fr][fs];
#pragma unroll
    for (int m = 0; m < 2; m++)
#pragma unroll
      for (int n = 0; n < NF; n++)
        acc[m][n] = __builtin_amdgcn_mfma_f32_16x16x32_bf16(af[m], bfr[n], acc[m][n], 0, 0, 0);
  };

  stage(0, 0);
  __syncthreads();
  for (int step = 0; step < 16; step++) {
    if (step < 15) stage(step + 1, (step + 1) & 1);
    compute(step & 1);
    __syncthreads();
  }

  // epilogue: C/D layout col=lane&15, row=(lane>>4)*4+j
  const int er = (l >> 4) * 4, ec = l & 15;
#pragma unroll
  for (int n = 0; n < NF; n++) {
    const int col = n0 + wc * (NT / 2) + n * 16 + ec;
    const float bv = bt[col & 511];
#pragma unroll
    for (int m = 0; m < 2; m++) {
      const int rowb = m0 + wr * 32 + m * 16 + er;
#pragma unroll
      for (int j = 0; j < 4; j++) {
        const int row = rowb + j;
        if (row < M) {
          float v = acc[m][n][j] + bv;
          if (resid) v += resid[(long)row * 512 + col];
          if (BF16OUT) ((short*)Cv)[(long)row * ldc + col] = f2bf(v);
          else ((float*)Cv)[(long)row * ldc + col] = v;
        }
      }
    }
  }
}

// ---------------- MFMA attention: 2048 blocks (b,qc,h), 4 waves x 16 q-rows ----
// XCD-bijective block swizzle: all 32 (qc,h) blocks of one batch b land on one
// XCD for QKV L2 reuse. Bias DMA'd conditionally (active waves only) into a
// per-wave LDS strip; reg loads issued BEFORE the DMAs so in-order vmcnt
// retirement lets S-MFMA run while DMAs are in flight. Unnormalized bf16 P
// overwrites the bias strip (all bias reads precede P writes; in-order LDS).
__global__ __launch_bounds__(256, 3) void k_attn(const short* __restrict__ QKVbf,
                                                 const float* __restrict__ bias,
                                                 const int* __restrict__ starts,
                                                 short* __restrict__ Obf) {
  __shared__ __align__(16) float BiasP[4][8][264];  // per-wave: 8 x (2 rows x 128 + 8 pad)
  __shared__ __align__(16) short Vtb[32][136];      // V transposed (rows = d)
  const int id = blockIdx.x;
  const int wg = (id & 7) * 256 + (id >> 3);  // bijective XCD swizzle (2048 % 8 == 0)
  const int b = wg >> 5, qc = (wg >> 4) & 1, h = wg & 15;
  const int tid = threadIdx.x, l = tid & 63, w = tid >> 6;
  const int wq0 = qc * 64 + w * 16;           // global q base of this wave
  const int lg = l >> 4, lk = l & 15, fs = lg * 8;
  short* Pw = (short*)&BiasP[w][0][0];        // P rows: 16 x 136 shorts, aliases strip

  const int s0 = starts[b], cnt = starts[b + 1] - s0;
  const bool active = wq0 < cnt;

  // ---- V reg loads: wave w owns k-rows w*32 .. w*32+31 (full 0..127 per block) ----
  const int u = l >> 2, c = (l & 3) * 8;
  const int vr0 = w * 32 + u, vr1 = vr0 + 16;
  const short* vbase = QKVbf + 1024 + h * 32 + c;
  const bf16x8 v0 = *(const bf16x8*)(vbase + (long)(s0 + min(vr0, cnt - 1)) * 1536);
  const bf16x8 v1 = *(const bf16x8*)(vbase + (long)(s0 + min(vr1, cnt - 1)) * 1536);

  // ---- Q/K fragment reg loads, THEN bias DMA (in-order retirement) ----
  bf16x8 aq, bk[8];
  if (active) {
    const short* qbase = QKVbf + h * 32 + fs;
    aq = *(const bf16x8*)(qbase + (long)(s0 + min(wq0 + lk, cnt - 1)) * 1536);
#pragma unroll
    for (int n = 0; n < 8; n++)
      bk[n] = *(const bf16x8*)(qbase + 512 + (long)(s0 + min(n * 16 + lk, cnt - 1)) * 1536);
    const float* bsrc = bias + ((long)(b * 16 + h) << 14) + (long)wq0 * 128 + l * 4;
#pragma unroll
    for (int t = 0; t < 8; t++)
      gl_lds16(bsrc + t * 256, &BiasP[w][t][0]);
  }

  // ---- V scatter-transpose into LDS (rows >= cnt finite, killed by P==0) ----
#pragma unroll
  for (int i = 0; i < 8; i++) Vtb[c + i][vr0] = v0[i];
#pragma unroll
  for (int i = 0; i < 8; i++) Vtb[c + i][vr1] = v1[i];

  f32x4 S[8];
  float invs[4];
  if (active) {
    // ---- S = Q K^T (8 MFMA) — needs only reg loads; DMAs still in flight ----
#pragma unroll
    for (int n = 0; n < 8; n++)
      S[n] = __builtin_amdgcn_mfma_f32_16x16x32_bf16(aq, bk[n],
                                                     (f32x4){0.f, 0.f, 0.f, 0.f}, 0, 0, 0);
    // drain the bias DMAs (no dest reg) before reading the strip
    asm volatile("s_waitcnt vmcnt(0)" ::: "memory");
    __builtin_amdgcn_sched_barrier(0);

    // ---- bias(LDS,f32) + scale + mask ----
#pragma unroll
    for (int n = 0; n < 8; n++) {
      const int k = n * 16 + lk;
      const bool kok = k < cnt;
#pragma unroll
      for (int j = 0; j < 4; j++) {
        const int r = lg * 4 + j;  // local q row 0..15
        const float sv = S[n][j] * SCALE_F + BiasP[w][r >> 1][(r & 1) * 128 + k];
        S[n][j] = kok ? sv : -1e30f;
      }
    }
    // ---- softmax (16-lane k-reduce); unnormalized bf16 P -> own strip ----
#pragma unroll
    for (int j = 0; j < 4; j++) {
      float mx = S[0][j];
#pragma unroll
      for (int n = 1; n < 8; n++) mx = fmaxf(mx, S[n][j]);
      mx = fmaxf(mx, __shfl_xor(mx, 1));
      mx = fmaxf(mx, __shfl_xor(mx, 2));
      mx = fmaxf(mx, __shfl_xor(mx, 4));
      mx = fmaxf(mx, __shfl_xor(mx, 8));
      float sum = 0.f;
#pragma unroll
      for (int n = 0; n < 8; n++) {
        const float p = __expf(S[n][j] - mx);
        S[n][j] = p;
        sum += p;
      }
      sum += __shfl_xor(sum, 1);
      sum += __shfl_xor(sum, 2);
      sum += __shfl_xor(sum, 4);
      sum += __shfl_xor(sum, 8);
      invs[j] = 1.f / sum;
      const int r = lg * 4 + j;
#pragma unroll
      for (int n = 0; n < 8; n++) Pw[r * 136 + n * 16 + lk] = f2bf(S[n][j]);
    }
  }

  __syncthreads();  // V (cross-wave) visibility; P/bias strips are wave-local
  if (!active) return;

  // ---- O = P V (8 MFMA), same-wave LDS RAW ----
  f32x4 O[2];
#pragma unroll
  for (int dt = 0; dt < 2; dt++) O[dt] = (f32x4){0.f, 0.f, 0.f, 0.f};
#pragma unroll
  for (int kc = 0; kc < 4; kc++) {
    const bf16x8 pa = *(const bf16x8*)&Pw[lk * 136 + kc * 32 + fs];
#pragma unroll
    for (int dt = 0; dt < 2; dt++) {
      const bf16x8 vb = *(const bf16x8*)&Vtb[dt * 16 + lk][kc * 32 + fs];
      O[dt] = __builtin_amdgcn_mfma_f32_16x16x32_bf16(pa, vb, O[dt], 0, 0, 0);
    }
  }
  // ---- store O (bf16), fold in 1/sum ----
#pragma unroll
  for (int j = 0; j < 4; j++) {
    const int q = wq0 + lg * 4 + j;
    if (q < cnt) {
      short* orow = Obf + (long)(s0 + q) * 512 + h * 32;
#pragma unroll
      for (int dt = 0; dt < 2; dt++)
        orow[dt * 16 + lk] = f2bf(O[dt][j] * invs[j]);
    }
  }
}

// ---------------- LayerNorm (residual pre-added), one wave per row ----------------
__global__ __launch_bounds__(256) void k_lnp(const float* __restrict__ pre,
                                             const float* __restrict__ lw,
                                             const float* __restrict__ lb,
                                             float* __restrict__ out) {
  const int row = blockIdx.x * 4 + (threadIdx.x >> 6);
  if (row >= NTOT) return;
  const int lane = threadIdx.x & 63;
  const float* pr = pre + (long)row * 512 + lane * 8;
  float4 p0 = *(const float4*)pr;
  float4 p1 = *(const float4*)(pr + 4);
  float v[8] = {p0.x, p0.y, p0.z, p0.w, p1.x, p1.y, p1.z, p1.w};
  float s = 0.f, s2 = 0.f;
#pragma unroll
  for (int j = 0; j < 8; j++) { s += v[j]; s2 += v[j] * v[j]; }
#pragma unroll
  for (int off = 32; off > 0; off >>= 1) {
    s += __shfl_xor(s, off);
    s2 += __shfl_xor(s2, off);
  }
  const float mu = s * (1.f / 512.f);
  const float var = s2 * (1.f / 512.f) - mu * mu;
  const float inv = rsqrtf(var + 1e-5f);
  float4 w0 = *(const float4*)&lw[lane * 8];
  float4 w1 = *(const float4*)&lw[lane * 8 + 4];
  float4 b0 = *(const float4*)&lb[lane * 8];
  float4 b1 = *(const float4*)&lb[lane * 8 + 4];
  float4 o0 = make_float4((v[0] - mu) * inv * w0.x + b0.x, (v[1] - mu) * inv * w0.y + b0.y,
                          (v[2] - mu) * inv * w0.z + b0.z, (v[3] - mu) * inv * w0.w + b0.w);
  float4 o1 = make_float4((v[4] - mu) * inv * w1.x + b1.x, (v[5] - mu) * inv * w1.y + b1.y,
                          (v[6] - mu) * inv * w1.z + b1.z, (v[7] - mu) * inv * w1.w + b1.w);
  float* dst = out + (long)row * 512 + lane * 8;
  *(float4*)dst = o0;
  *(float4*)(dst + 4) = o1;
}

extern "C" void kernel_launch(void* const* d_in, const int* in_sizes, int n_in,
                              void* d_out, int out_size, void* d_ws, size_t ws_size,
                              hipStream_t stream) {
  const float* x = (const float*)d_in[0];
  const float* attn_bias = (const float*)d_in[1];
  const float* Wq = (const float*)d_in[2];
  const float* bq = (const float*)d_in[3];
  const float* Wk = (const float*)d_in[4];
  const float* bk = (const float*)d_in[5];
  const float* Wv = (const float*)d_in[6];
  const float* bv = (const float*)d_in[7];
  const float* Wp = (const float*)d_in[8];
  const float* bp = (const float*)d_in[9];
  const float* ln_w = (const float*)d_in[10];
  const float* ln_b = (const float*)d_in[11];
  const int* batch = (const int*)d_in[12];
  float* out = (float*)d_out;

  char* ws = (char*)d_ws;
  int* starts = (int*)ws;                        // 65 ints (512B reserved)
  short* Xbf = (short*)(ws + 512);               // NTOT x 512 bf16
  short* Wqb = Xbf + (long)NTOT * 512;
  short* Wkb = Wqb + 512 * 512;
  short* Wvb = Wkb + 512 * 512;
  short* Wpb = Wvb + 512 * 512;
  short* QKVbf = Wpb + 512 * 512;                // NTOT x 1536 bf16
  short* Obf = Xbf;                              // reuse: Xbf dead after QKV GEMM
  float* proj = (float*)QKVbf;                   // reuse: QKVbf dead after attention

  k_starts<<<(NTOT + 255) / 256, 256, 0, stream>>>(batch, starts);
  k_cvt<<<1537 + 4 * 128, 256, 0, stream>>>(x, Wq, Wk, Wv, Wp, Xbf, Wqb, Wkb, Wvb, Wpb);

  dim3 gq(12, (NTOT + 63) / 64);  // fused QKV: N = 1536, 64x128 tiles, bf16 out
  k_gemm_mfma<128, true><<<gq, 256, 0, stream>>>(Xbf, Wqb, Wkb, Wvb, bq, bk, bv,
                                                 nullptr, QKVbf, 1536, NTOT);

  k_attn<<<2048, 256, 0, stream>>>(QKVbf, attn_bias, starts, Obf);

  dim3 gp(8, (NTOT + 63) / 64);  // proj: N = 512, 64x64 tiles, residual fused, f32 out
  k_gemm_mfma<64, false><<<gp, 256, 0, stream>>>(Obf, Wpb, Wpb, Wpb, bp, bp, bp,
                                                 x, proj, 512, NTOT);

  k_lnp<<<(NTOT + 3) / 4, 256, 0, stream>>>(proj, ln_w, ln_b, out);
}

// Round 13
// 75.539 us; speedup vs baseline: 1.3890x; 1.0785x over previous
//
#include <hip/hip_runtime.h>
#include <math.h>

#define NTOT 6148
#define NB 64
#define DM 512
#define SCALE_F 0.17677669529663687f

typedef __attribute__((ext_vector_type(8))) short bf16x8;
typedef __attribute__((ext_vector_type(4))) float f32x4;

__device__ __forceinline__ short f2bf(float f) {
  union { float f; unsigned u; } v; v.f = f;
  unsigned r = (v.u + 0x7fffu + ((v.u >> 16) & 1u)) >> 16;
  return (short)r;
}

__device__ __forceinline__ void gl_lds16(const void* g, void* l) {
  auto gp = (const __attribute__((address_space(1))) unsigned*)(unsigned long long)(uintptr_t)g;
  auto lp = (__attribute__((address_space(3))) unsigned*)(unsigned long long)(uintptr_t)l;
  __builtin_amdgcn_global_load_lds(gp, lp, 16, 0, 0);
}

// ---------------- f32 -> bf16 conversion (x + 4 weights) + starts (fused) ----------------
__global__ __launch_bounds__(256) void k_cvt(const float* __restrict__ x,
                                             const float* __restrict__ wq,
                                             const float* __restrict__ wk,
                                             const float* __restrict__ wv,
                                             const float* __restrict__ wp,
                                             short* __restrict__ xb,
                                             short* __restrict__ wqb,
                                             short* __restrict__ wkb,
                                             short* __restrict__ wvb,
                                             short* __restrict__ wpb,
                                             const int* __restrict__ batch,
                                             int* __restrict__ starts) {
  const int bid = blockIdx.x;
  if (bid < 25) {  // fused starts computation (saves a launch)
    const int i = bid * 256 + threadIdx.x;
    if (i < NTOT) {
      const int bb = batch[i];
      if (i == 0) starts[bb] = 0;
      else if (batch[i - 1] != bb) starts[bb] = i;
      if (i == NTOT - 1) starts[NB] = NTOT;
    }
  }
  const float* s; short* d; long off;
  if (bid < 1537) {  // 1537*2048 == NTOT*512 exactly
    s = x; d = xb;
    off = ((long)bid * 256 + threadIdx.x) * 8;
  } else {
    int wi = (bid - 1537) >> 7;  // 128 blocks per 512x512 matrix
    s = (wi == 0) ? wq : (wi == 1) ? wk : (wi == 2) ? wv : wp;
    d = (wi == 0) ? wqb : (wi == 1) ? wkb : (wi == 2) ? wvb : wpb;
    off = ((long)((bid - 1537) & 127) * 256 + threadIdx.x) * 8;
  }
  float4 v0 = *(const float4*)(s + off);
  float4 v1 = *(const float4*)(s + off + 4);
  bf16x8 o;
  o[0] = f2bf(v0.x); o[1] = f2bf(v0.y); o[2] = f2bf(v0.z); o[3] = f2bf(v0.w);
  o[4] = f2bf(v1.x); o[5] = f2bf(v1.y); o[6] = f2bf(v1.z); o[7] = f2bf(v1.w);
  *(bf16x8*)(d + off) = o;
}

// ---------------- bf16 MFMA GEMM, 64xNT tile (grid-TLP oriented) ----------------
// C = A[M][512](bf16) @ W[N][512](bf16)^T + bias. BK=32, 4 waves (2x2 of 32xNT/2).
template <int NT, bool BF16OUT>
__global__ __launch_bounds__(256) void k_gemm_mfma(
    const short* __restrict__ Abf,
    const short* __restrict__ W0, const short* __restrict__ W1, const short* __restrict__ W2,
    const float* __restrict__ b0, const float* __restrict__ b1, const float* __restrict__ b2,
    const float* __restrict__ resid, void* __restrict__ Cv, int ldc, int M) {
  constexpr int NF = NT / 32;  // n-frags per wave
  __shared__ __align__(16) short As[2][64][32];
  __shared__ __align__(16) short Bs[2][NT][32];
  const int tid = threadIdx.x;
  const int w = tid >> 6, l = tid & 63;
  const int m0 = blockIdx.y * 64;
  const int n0 = blockIdx.x * NT;
  const int sel = n0 >> 9;
  const short* Wt = (sel == 0) ? W0 : (sel == 1) ? W1 : W2;
  const float* bt = (sel == 0) ? b0 : (sel == 1) ? b1 : b2;
  const int nl0 = n0 & 511;
  const int wr = w >> 1, wc = w & 1;
  const int lr = l >> 2;        // 0..15: row within a 16-row (1KB) DMA chunk
  const int lc = (l & 3) * 8;   // short offset of this lane's 16B piece
  const int fr = l & 15, fs = (l >> 4) * 8;

  const long gaA = (long)min(m0 + w * 16 + lr, M - 1) * 512 + lc;       // A: 16 rows/wave
  const long gaB0 = (long)(nl0 + ((NT == 128) ? w * 32 : w * 16) + lr) * 512 + lc;
  const long gaB1 = (long)(nl0 + w * 32 + 16 + lr) * 512 + lc;          // only NT=128

  f32x4 acc[2][NF];
#pragma unroll
  for (int m = 0; m < 2; m++)
#pragma unroll
    for (int n = 0; n < NF; n++) acc[m][n] = (f32x4){0.f, 0.f, 0.f, 0.f};

  auto stage = [&](int kt, int buf) {
    const int k0 = kt * 32;
    gl_lds16(Abf + gaA + k0, &As[buf][w * 16][0]);
    if (NT == 128) {
      gl_lds16(Wt + gaB0 + k0, &Bs[buf][w * 32][0]);
      gl_lds16(Wt + gaB1 + k0, &Bs[buf][w * 32 + 16][0]);
    } else {
      gl_lds16(Wt + gaB0 + k0, &Bs[buf][w * 16][0]);
    }
  };
  auto compute = [&](int buf) {
    bf16x8 af[2], bfr[NF];
#pragma unroll
    for (int m = 0; m < 2; m++) af[m] = *(const bf16x8*)&As[buf][wr * 32 + m * 16 + fr][fs];
#pragma unroll
    for (int n = 0; n < NF; n++)
      bfr[n] = *(const bf16x8*)&Bs[buf][wc * (NT / 2) + n * 16 + fr][fs];
#pragma unroll
    for (int m = 0; m < 2; m++)
#pragma unroll
      for (int n = 0; n < NF; n++)
        acc[m][n] = __builtin_amdgcn_mfma_f32_16x16x32_bf16(af[m], bfr[n], acc[m][n], 0, 0, 0);
  };

  stage(0, 0);
  __syncthreads();
  for (int step = 0; step < 16; step++) {
    if (step < 15) stage(step + 1, (step + 1) & 1);
    compute(step & 1);
    __syncthreads();
  }

  // epilogue: C/D layout col=lane&15, row=(lane>>4)*4+j
  const int er = (l >> 4) * 4, ec = l & 15;
#pragma unroll
  for (int n = 0; n < NF; n++) {
    const int col = n0 + wc * (NT / 2) + n * 16 + ec;
    const float bv = bt[col & 511];
#pragma unroll
    for (int m = 0; m < 2; m++) {
      const int rowb = m0 + wr * 32 + m * 16 + er;
#pragma unroll
      for (int j = 0; j < 4; j++) {
        const int row = rowb + j;
        if (row < M) {
          float v = acc[m][n][j] + bv;
          if (resid) v += resid[(long)row * 512 + col];
          if (BF16OUT) ((short*)Cv)[(long)row * ldc + col] = f2bf(v);
          else ((float*)Cv)[(long)row * ldc + col] = v;
        }
      }
    }
  }
}

// ---------------- MFMA attention: 2048 blocks (b,qc,h), 4 waves x 16 q-rows ----
// Bias loaded DIRECTLY to VGPRs in S-fragment layout (32 dwords/lane, 4x64B
// coalesced segments per load). No LDS staging, no vmcnt(0) drain — compiler
// emits counted vmcnt before each use, so softmax overlaps in-flight loads.
// P gets a dedicated per-wave LDS strip; V^T is block-shared LDS.
__global__ __launch_bounds__(256, 2) void k_attn(const short* __restrict__ QKVbf,
                                                 const float* __restrict__ bias,
                                                 const int* __restrict__ starts,
                                                 short* __restrict__ Obf) {
  __shared__ __align__(16) short Ps[4][16][136];  // per-wave unnormalized P
  __shared__ __align__(16) short Vtb[32][136];    // V transposed (rows = d)
  const int id = blockIdx.x;
  const int wg = (id & 7) * 256 + (id >> 3);  // bijective XCD swizzle (2048 % 8 == 0)
  const int b = wg >> 5, qc = (wg >> 4) & 1, h = wg & 15;
  const int tid = threadIdx.x, l = tid & 63, w = tid >> 6;
  const int wq0 = qc * 64 + w * 16;           // global q base of this wave
  const int lg = l >> 4, lk = l & 15, fs = lg * 8;

  const int s0 = starts[b], cnt = starts[b + 1] - s0;
  const bool active = wq0 < cnt;

  // ---- V reg loads: wave w owns k-rows w*32 .. w*32+31 (full 0..127 per block) ----
  const int u = l >> 2, c = (l & 3) * 8;
  const int vr0 = w * 32 + u, vr1 = vr0 + 16;
  const short* vbase = QKVbf + 1024 + h * 32 + c;
  const bf16x8 v0 = *(const bf16x8*)(vbase + (long)(s0 + min(vr0, cnt - 1)) * 1536);
  const bf16x8 v1 = *(const bf16x8*)(vbase + (long)(s0 + min(vr1, cnt - 1)) * 1536);

  // ---- Q/K fragment reg loads + bias reg loads (all in flight together) ----
  bf16x8 aq, bk[8];
  float bv[8][4];  // bias[q=wq0+lg*4+j][k=n*16+lk]
  if (active) {
    const short* qbase = QKVbf + h * 32 + fs;
    aq = *(const bf16x8*)(qbase + (long)(s0 + min(wq0 + lk, cnt - 1)) * 1536);
#pragma unroll
    for (int n = 0; n < 8; n++)
      bk[n] = *(const bf16x8*)(qbase + 512 + (long)(s0 + min(n * 16 + lk, cnt - 1)) * 1536);
    const float* bb = bias + ((long)(b * 16 + h) << 14) + (long)(wq0 + lg * 4) * 128 + lk;
#pragma unroll
    for (int n = 0; n < 8; n++)
#pragma unroll
      for (int j = 0; j < 4; j++) bv[n][j] = bb[j * 128 + n * 16];
  }

  // ---- V scatter-transpose into LDS (rows >= cnt finite, killed by P==0) ----
#pragma unroll
  for (int i = 0; i < 8; i++) Vtb[c + i][vr0] = v0[i];
#pragma unroll
  for (int i = 0; i < 8; i++) Vtb[c + i][vr1] = v1[i];

  float invs[4];
  if (active) {
    // ---- S = Q K^T (8 MFMA) ----
    f32x4 S[8];
#pragma unroll
    for (int n = 0; n < 8; n++)
      S[n] = __builtin_amdgcn_mfma_f32_16x16x32_bf16(aq, bk[n],
                                                     (f32x4){0.f, 0.f, 0.f, 0.f}, 0, 0, 0);
    // ---- bias(reg) + scale + mask (compiler-counted waits per bv use) ----
#pragma unroll
    for (int n = 0; n < 8; n++) {
      const int k = n * 16 + lk;
      const bool kok = k < cnt;
#pragma unroll
      for (int j = 0; j < 4; j++) {
        const float sv = S[n][j] * SCALE_F + bv[n][j];
        S[n][j] = kok ? sv : -1e30f;
      }
    }
    // ---- softmax (16-lane k-reduce); unnormalized bf16 P -> own strip ----
#pragma unroll
    for (int j = 0; j < 4; j++) {
      float mx = S[0][j];
#pragma unroll
      for (int n = 1; n < 8; n++) mx = fmaxf(mx, S[n][j]);
      mx = fmaxf(mx, __shfl_xor(mx, 1));
      mx = fmaxf(mx, __shfl_xor(mx, 2));
      mx = fmaxf(mx, __shfl_xor(mx, 4));
      mx = fmaxf(mx, __shfl_xor(mx, 8));
      float sum = 0.f;
#pragma unroll
      for (int n = 0; n < 8; n++) {
        const float p = __expf(S[n][j] - mx);
        S[n][j] = p;
        sum += p;
      }
      sum += __shfl_xor(sum, 1);
      sum += __shfl_xor(sum, 2);
      sum += __shfl_xor(sum, 4);
      sum += __shfl_xor(sum, 8);
      invs[j] = 1.f / sum;
      const int r = lg * 4 + j;
#pragma unroll
      for (int n = 0; n < 8; n++) Ps[w][r][n * 16 + lk] = f2bf(S[n][j]);
    }
  }

  __syncthreads();  // V (cross-wave) visibility; P strips are wave-local
  if (!active) return;

  // ---- O = P V (8 MFMA), same-wave LDS RAW ----
  f32x4 O[2];
#pragma unroll
  for (int dt = 0; dt < 2; dt++) O[dt] = (f32x4){0.f, 0.f, 0.f, 0.f};
#pragma unroll
  for (int kc = 0; kc < 4; kc++) {
    const bf16x8 pa = *(const bf16x8*)&Ps[w][lk][kc * 32 + fs];
#pragma unroll
    for (int dt = 0; dt < 2; dt++) {
      const bf16x8 vb = *(const bf16x8*)&Vtb[dt * 16 + lk][kc * 32 + fs];
      O[dt] = __builtin_amdgcn_mfma_f32_16x16x32_bf16(pa, vb, O[dt], 0, 0, 0);
    }
  }
  // ---- store O (bf16), fold in 1/sum ----
#pragma unroll
  for (int j = 0; j < 4; j++) {
    const int q = wq0 + lg * 4 + j;
    if (q < cnt) {
      short* orow = Obf + (long)(s0 + q) * 512 + h * 32;
#pragma unroll
      for (int dt = 0; dt < 2; dt++)
        orow[dt * 16 + lk] = f2bf(O[dt][j] * invs[j]);
    }
  }
}

// ---------------- LayerNorm (residual pre-added), one wave per row ----------------
__global__ __launch_bounds__(256) void k_lnp(const float* __restrict__ pre,
                                             const float* __restrict__ lw,
                                             const float* __restrict__ lb,
                                             float* __restrict__ out) {
  const int row = blockIdx.x * 4 + (threadIdx.x >> 6);
  if (row >= NTOT) return;
  const int lane = threadIdx.x & 63;
  const float* pr = pre + (long)row * 512 + lane * 8;
  float4 p0 = *(const float4*)pr;
  float4 p1 = *(const float4*)(pr + 4);
  float v[8] = {p0.x, p0.y, p0.z, p0.w, p1.x, p1.y, p1.z, p1.w};
  float s = 0.f, s2 = 0.f;
#pragma unroll
  for (int j = 0; j < 8; j++) { s += v[j]; s2 += v[j] * v[j]; }
#pragma unroll
  for (int off = 32; off > 0; off >>= 1) {
    s += __shfl_xor(s, off);
    s2 += __shfl_xor(s2, off);
  }
  const float mu = s * (1.f / 512.f);
  const float var = s2 * (1.f / 512.f) - mu * mu;
  const float inv = rsqrtf(var + 1e-5f);
  float4 w0 = *(const float4*)&lw[lane * 8];
  float4 w1 = *(const float4*)&lw[lane * 8 + 4];
  float4 b0 = *(const float4*)&lb[lane * 8];
  float4 b1 = *(const float4*)&lb[lane * 8 + 4];
  float4 o0 = make_float4((v[0] - mu) * inv * w0.x + b0.x, (v[1] - mu) * inv * w0.y + b0.y,
                          (v[2] - mu) * inv * w0.z + b0.z, (v[3] - mu) * inv * w0.w + b0.w);
  float4 o1 = make_float4((v[4] - mu) * inv * w1.x + b1.x, (v[5] - mu) * inv * w1.y + b1.y,
                          (v[6] - mu) * inv * w1.z + b1.z, (v[7] - mu) * inv * w1.w + b1.w);
  float* dst = out + (long)row * 512 + lane * 8;
  *(float4*)dst = o0;
  *(float4*)(dst + 4) = o1;
}

extern "C" void kernel_launch(void* const* d_in, const int* in_sizes, int n_in,
                              void* d_out, int out_size, void* d_ws, size_t ws_size,
                              hipStream_t stream) {
  const float* x = (const float*)d_in[0];
  const float* attn_bias = (const float*)d_in[1];
  const float* Wq = (const float*)d_in[2];
  const float* bq = (const float*)d_in[3];
  const float* Wk = (const float*)d_in[4];
  const float* bk = (const float*)d_in[5];
  const float* Wv = (const float*)d_in[6];
  const float* bv = (const float*)d_in[7];
  const float* Wp = (const float*)d_in[8];
  const float* bp = (const float*)d_in[9];
  const float* ln_w = (const float*)d_in[10];
  const float* ln_b = (const float*)d_in[11];
  const int* batch = (const int*)d_in[12];
  float* out = (float*)d_out;

  char* ws = (char*)d_ws;
  int* starts = (int*)ws;                        // 65 ints (512B reserved)
  short* Xbf = (short*)(ws + 512);               // NTOT x 512 bf16
  short* Wqb = Xbf + (long)NTOT * 512;
  short* Wkb = Wqb + 512 * 512;
  short* Wvb = Wkb + 512 * 512;
  short* Wpb = Wvb + 512 * 512;
  short* QKVbf = Wpb + 512 * 512;                // NTOT x 1536 bf16
  short* Obf = Xbf;                              // reuse: Xbf dead after QKV GEMM
  float* proj = (float*)QKVbf;                   // reuse: QKVbf dead after attention

  k_cvt<<<1537 + 4 * 128, 256, 0, stream>>>(x, Wq, Wk, Wv, Wp, Xbf, Wqb, Wkb, Wvb, Wpb,
                                            batch, starts);

  dim3 gq(12, (NTOT + 63) / 64);  // fused QKV: N = 1536, 64x128 tiles, bf16 out
  k_gemm_mfma<128, true><<<gq, 256, 0, stream>>>(Xbf, Wqb, Wkb, Wvb, bq, bk, bv,
                                                 nullptr, QKVbf, 1536, NTOT);

  k_attn<<<2048, 256, 0, stream>>>(QKVbf, attn_bias, starts, Obf);

  dim3 gp(8, (NTOT + 63) / 64);  // proj: N = 512, 64x64 tiles, residual fused, f32 out
  k_gemm_mfma<64, false><<<gp, 256, 0, stream>>>(Obf, Wpb, Wpb, Wpb, bp, bp, bp,
                                                 x, proj, 512, NTOT);

  k_lnp<<<(NTOT + 3) / 4, 256, 0, stream>>>(proj, ln_w, ln_b, out);
}